// Round 20
// baseline (219.188 us; speedup 1.0000x reference)
//
#include <hip/hip_runtime.h>
#include <stdint.h>

#define S_LEN 1024
#define DIM   1024
#define NHID  64
#define NHEAD 16
#define NB    4

typedef __bf16 bf16x8 __attribute__((ext_vector_type(8)));
typedef float  f32x4  __attribute__((ext_vector_type(4)));
typedef unsigned short u16;

__device__ __forceinline__ u16 f2b(float f) {
  unsigned u = __float_as_uint(f);
  u += 0x7FFFu + ((u >> 16) & 1u);          // round-to-nearest-even
  return (u16)(u >> 16);
}

__device__ __forceinline__ f32x4 mfma16(bf16x8 a, bf16x8 b, f32x4 c) {
  return __builtin_amdgcn_mfma_f32_16x16x32_bf16(a, b, c, 0, 0, 0);
}

// ---------------- fused prep: cvt_x + maskbits + 4 transposes, one launch ----------------
__device__ __forceinline__ void transpose_tile(const float* __restrict__ ip,
                                               u16* __restrict__ op,
                                               int R, int C, int r0, int c0,
                                               float (*tile)[65], int t) {
  {
    int col = t & 63, rr = t >> 6;
#pragma unroll
    for (int p = 0; p < 8; ++p) {
      int r = p * 4 + rr;
      tile[r][col] = ip[(size_t)(r0 + r) * C + c0 + col];
    }
  }
  __syncthreads();
  {
    int d = t & 31, er = t >> 5;
#pragma unroll
    for (int p = 0; p < 8; ++p) {
      int e = p * 8 + er;
      op[(size_t)(c0 + e) * R + r0 + d] = f2b(tile[d][e]);
    }
  }
}

__global__ __launch_bounds__(256) void k_prep(const float* __restrict__ x,
                                              const int* __restrict__ mask,
                                              const float* __restrict__ Wq,
                                              const float* __restrict__ Wk,
                                              const float* __restrict__ Wv,
                                              const float* __restrict__ Wo,
                                              u16* __restrict__ xb,
                                              uint32_t* __restrict__ mbits,
                                              u16* __restrict__ Wtb,
                                              u16* __restrict__ Wotb) {
  __shared__ float tile[32][65];
  int blk = blockIdx.x, t = threadIdx.x;
  if (blk < 4096) {
    int i = blk * 256 + t;
    float4 v = ((const float4*)x)[i];
    ushort4 o;
    o.x = f2b(v.x); o.y = f2b(v.y); o.z = f2b(v.z); o.w = f2b(v.w);
    ((ushort4*)xb)[i] = o;
  } else if (blk < 4608) {
    int w = (blk - 4096) * 256 + t;
    const int4* mp = (const int4*)mask + (size_t)w * 8;
    uint32_t v = 0;
#pragma unroll
    for (int i = 0; i < 8; ++i) {
      int4 m = mp[i];
      v |= (m.x != 0 ? 1u : 0u) << (i * 4 + 0);
      v |= (m.y != 0 ? 1u : 0u) << (i * 4 + 1);
      v |= (m.z != 0 ? 1u : 0u) << (i * 4 + 2);
      v |= (m.w != 0 ? 1u : 0u) << (i * 4 + 3);
    }
    mbits[w] = v;
  } else if (blk < 6144) {
    int rel = blk - 4608;                 // 0..1535
    int sel = rel >> 9;                   // /512 -> 0,1,2
    int r2 = rel & 511;
    int batch = r2 >> 5;                  // 0..15
    int r0 = (r2 & 31) * 32;
    const float* W = (sel == 0) ? Wq : (sel == 1) ? Wk : Wv;
    transpose_tile(W + (size_t)batch * 65536,
                   Wtb + (size_t)sel * 1048576 + (size_t)batch * 65536,
                   1024, 64, r0, 0, tile, t);
  } else {
    int rel = blk - 6144;                 // 0..511
    int r0 = (rel >> 4) * 32;
    int c0 = (rel & 15) * 64;
    transpose_tile(Wo, Wotb, 1024, 1024, r0, c0, tile, t);
  }
}

// ---------------- QKV projection: [4096,1024] @ Wt[sel][1024 n][1024 k] ----------------
// Q output is pre-scaled by 0.5 (folds softmax 1/SCALE; exact in bf16)
__global__ __launch_bounds__(256) void k_qkv(const u16* __restrict__ xb,
                                             const u16* __restrict__ Wtb,
                                             const float* __restrict__ bq,
                                             const float* __restrict__ bk,
                                             const float* __restrict__ bv,
                                             u16* __restrict__ Qb,
                                             u16* __restrict__ Kb,
                                             u16* __restrict__ Vtb) {
  __shared__ __align__(16) char lds[32768];
  int t = threadIdx.x, w = t >> 6, lane = t & 63;
  int l15 = lane & 15, l4 = lane >> 4;
  int m0 = blockIdx.x * 128, n0 = blockIdx.y * 128, sel = blockIdx.z;
  const u16* Wh = Wtb + (size_t)sel * (NHEAD * NHID * DIM);
  int wr = w >> 1, wc = w & 1;

  f32x4 acc[4][4];
  const f32x4 fz = {0.f, 0.f, 0.f, 0.f};
#pragma unroll
  for (int i = 0; i < 4; ++i)
#pragma unroll
    for (int j = 0; j < 4; ++j) acc[i][j] = fz;

  for (int kk = 0; kk < 16; ++kk) {
    int k0 = kk * 64;
#pragma unroll
    for (int c = 0; c < 4; ++c) {
      int idx = c * 256 + t, r = idx >> 3, cb = idx & 7;
      int4 v = *(const int4*)(xb + (size_t)(m0 + r) * DIM + k0 + cb * 8);
      *(int4*)(lds + r * 128 + ((cb * 16) ^ ((r & 7) << 4))) = v;
    }
#pragma unroll
    for (int c = 0; c < 4; ++c) {
      int idx = c * 256 + t, r = idx >> 3, cb = idx & 7;
      int4 v = *(const int4*)(Wh + (size_t)(n0 + r) * DIM + k0 + cb * 8);
      *(int4*)(lds + 16384 + r * 128 + ((cb * 16) ^ ((r & 7) << 4))) = v;
    }
    __syncthreads();
    bf16x8 a[4][2], bb[4][2];
#pragma unroll
    for (int mf = 0; mf < 4; ++mf)
#pragma unroll
      for (int kc = 0; kc < 2; ++kc) {
        int row = wr * 64 + mf * 16 + l15;
        int kb = kc * 64 + l4 * 16;
        a[mf][kc] = *(const bf16x8*)(lds + row * 128 + (kb ^ ((row & 7) << 4)));
      }
#pragma unroll
    for (int nf = 0; nf < 4; ++nf)
#pragma unroll
      for (int kc = 0; kc < 2; ++kc) {
        int row = wc * 64 + nf * 16 + l15;
        int kb = kc * 64 + l4 * 16;
        bb[nf][kc] = *(const bf16x8*)(lds + 16384 + row * 128 + (kb ^ ((row & 7) << 4)));
      }
#pragma unroll
    for (int kc = 0; kc < 2; ++kc)
#pragma unroll
      for (int mf = 0; mf < 4; ++mf)
#pragma unroll
        for (int nf = 0; nf < 4; ++nf)
          acc[mf][nf] = mfma16(a[mf][kc], bb[nf][kc], acc[mf][nf]);
    __syncthreads();
  }

  const float* bias = (sel == 0) ? bq : (sel == 1) ? bk : bv;
  float postScale = (sel == 0) ? 0.5f : 1.0f;
#pragma unroll
  for (int nf = 0; nf < 4; ++nf) {
    int n = n0 + wc * 64 + nf * 16 + l15;
    int h = n >> 6, e = n & 63;
    float bv_ = bias[n];
#pragma unroll
    for (int mf = 0; mf < 4; ++mf) {
      int mrow0 = m0 + wr * 64 + mf * 16 + l4 * 4;
      int b_ = mrow0 >> 10, s0 = mrow0 & 1023;
      if (sel == 2) {
        ushort4 pk;
        pk.x = f2b(acc[mf][nf][0] + bv_);
        pk.y = f2b(acc[mf][nf][1] + bv_);
        pk.z = f2b(acc[mf][nf][2] + bv_);
        pk.w = f2b(acc[mf][nf][3] + bv_);
        *(ushort4*)(Vtb + ((size_t)(b_ * NHEAD + h) * NHID + e) * S_LEN + s0) = pk;
      } else {
        u16* dst = (sel == 0) ? Qb : Kb;
#pragma unroll
        for (int j = 0; j < 4; ++j)
          dst[((size_t)(b_ * NHEAD + h) * S_LEN + s0 + j) * NHID + e] =
              f2b((acc[mf][nf][j] + bv_) * postScale);
      }
    }
  }
}

// ---------------- fused attention: 8 waves (512 thr), UNCAPPED VGPR ----------------
// R9's kernel minus the forced min-waves bound: same work per block (each wave
// owns a 128-key slice of 16 q rows), LDS 33KB -> 1 block/CU, but 8 waves =
// 2 waves/SIMD for latency hiding on the phase-1 dependent chain.
__global__ __launch_bounds__(512) void k_attn(const u16* __restrict__ Qb,
                                              const u16* __restrict__ Kb,
                                              const u16* __restrict__ Vtb,
                                              const uint32_t* __restrict__ mbitsG,
                                              float* __restrict__ alphaOut,
                                              u16* __restrict__ Ob) {
  __shared__ __align__(16) char smem[33280];   // P[16][2048B] + redS[8][16] f32
  float* redS = (float*)(smem + 32768);
  int t = threadIdx.x, w = t >> 6, lane = t & 63;
  int l15 = lane & 15, l4 = lane >> 4;
  int q0 = blockIdx.x * 16;
  int bh = blockIdx.y, b = bh >> 4, hh = bh & 15;
  const u16* Qh = Qb + (size_t)bh * S_LEN * NHID;
  const u16* Kh = Kb + (size_t)bh * S_LEN * NHID;
  const u16* Vh = Vtb + (size_t)bh * NHID * S_LEN;
  int kbase = w * 128;

  // mask bits for this lane's q-row, this wave's 128 keys: 4 u32 in one uint4
  uint4 mw = *(const uint4*)(mbitsG + ((size_t)b * S_LEN + q0 + l15) * 32 + w * 4);

  // Q fragments (pre-scaled by 0.5): B-operand, col = q = l15, k = ec*32 + l4*8
  bf16x8 aq[2];
#pragma unroll
  for (int ec = 0; ec < 2; ++ec)
    aq[ec] = *(const bf16x8*)(Qh + (size_t)(q0 + l15) * NHID + ec * 32 + l4 * 8);

  const f32x4 fz = {0.f, 0.f, 0.f, 0.f};

  // ---- phase 1: QK^T + exp + mask + stage to P; slice sums on the fly ----
  float s0 = 0.f, s1 = 0.f, s2 = 0.f, s3 = 0.f;
#pragma unroll
  for (int kf = 0; kf < 8; ++kf) {
    int key = kbase + kf * 16 + l15;
    bf16x8 kb0 = *(const bf16x8*)(Kh + (size_t)key * NHID + l4 * 8);
    bf16x8 kb1 = *(const bf16x8*)(Kh + (size_t)key * NHID + 32 + l4 * 8);
    f32x4 sct = fz;
    sct = mfma16(kb0, aq[0], sct);              // D[key][q]
    sct = mfma16(kb1, aq[1], sct);
    float e0 = __expf(sct[0]);
    float e1 = __expf(sct[1]);
    float e2 = __expf(sct[2]);
    float e3 = __expf(sct[3]);
    s0 += e0; s1 += e1; s2 += e2; s3 += e3;     // UNMASKED sums (per reference)
    uint32_t mword;
    switch (kf >> 1) {
      case 0: mword = mw.x; break;
      case 1: mword = mw.y; break;
      case 2: mword = mw.z; break;
      default: mword = mw.w; break;
    }
    int bbase = ((kf & 1) << 4) + l4 * 4;
    uint32_t am01 = (((mword >> (bbase + 0)) & 1u) ? 0x0000FFFFu : 0u) |
                    (((mword >> (bbase + 1)) & 1u) ? 0xFFFF0000u : 0u);
    uint32_t am23 = (((mword >> (bbase + 2)) & 1u) ? 0x0000FFFFu : 0u) |
                    (((mword >> (bbase + 3)) & 1u) ? 0xFFFF0000u : 0u);
    uint2 pk;
    pk.x = ((uint32_t)f2b(e0) | ((uint32_t)f2b(e1) << 16)) & am01;
    pk.y = ((uint32_t)f2b(e2) | ((uint32_t)f2b(e3) << 16)) & am23;
    *(uint2*)(smem + l15 * 2048 +
              (((kbase + kf * 16 + l4 * 4) * 2) ^ ((l15 & 7) << 4))) = pk;
  }
  float ls = (s0 + s1) + (s2 + s3);
  ls += __shfl_xor(ls, 16);
  ls += __shfl_xor(ls, 32);                     // slice sum for q-row l15
  if (lane < 16) redS[w * 16 + l15] = ls;
  __syncthreads();                              // P + redS visible to all waves

  auto rowInv = [&](int r) {
    float s = 0.f;
#pragma unroll
    for (int wi = 0; wi < 8; ++wi) s += redS[wi * 16 + r];
    return 1.f / s;
  };

  float* abW = alphaOut + (size_t)bh * S_LEN * S_LEN;
  f32x4 o[4];
#pragma unroll
  for (int ef = 0; ef < 4; ++ef) o[ef] = fz;

  // phase 2a: each wave writes 2 full alpha rows, 1KB contiguous per instruction.
  auto rw = [&](int rr) {
    int r = w * 2 + rr;
    float invr = rowInv(r);
    float* dst = abW + (size_t)(q0 + r) * S_LEN;
#pragma unroll
    for (int seg = 0; seg < 4; ++seg) {
      int raw = seg * 512 + lane * 8;           // linear byte offset in P row
      int boff = raw ^ ((r & 7) << 4);          // swizzled LDS address
      uint2 pk = *(const uint2*)(smem + r * 2048 + boff);
      f32x4 av;
      av[0] = __uint_as_float(pk.x << 16) * invr;
      av[1] = __uint_as_float(pk.x & 0xFFFF0000u) * invr;
      av[2] = __uint_as_float(pk.y << 16) * invr;
      av[3] = __uint_as_float(pk.y & 0xFFFF0000u) * invr;
      __builtin_nontemporal_store(av, (f32x4*)(dst + (raw >> 1)));
    }
  };
  // phase 2b: PV over own 128-key slice from LDS P
  auto pvc = [&](int c) {
#pragma unroll
    for (int kc2 = 0; kc2 < 2; ++kc2) {
      bf16x8 pa = *(const bf16x8*)(smem + l15 * 2048 +
          ((((kbase + c * 64 + kc2 * 32) * 2) + l4 * 16) ^ ((l15 & 7) << 4)));
#pragma unroll
      for (int ef = 0; ef < 4; ++ef) {
        int e = ef * 16 + l15;
        bf16x8 vb = *(const bf16x8*)(Vh + (size_t)e * S_LEN + kbase + c * 64 +
                                     kc2 * 32 + l4 * 8);
        o[ef] = mfma16(pa, vb, o[ef]);
      }
    }
  };

  rw(0); pvc(0);
  rw(1); pvc(1);

  // epilogue: cross-wave O reduction (redO aliases P), scale by inv
  __syncthreads();
  float* redO = (float*)smem;                   // [8 w][16 q][64 e] = 32KB
#pragma unroll
  for (int ef = 0; ef < 4; ++ef)
#pragma unroll
    for (int j = 0; j < 4; ++j)
      redO[w * 1024 + (l4 * 4 + j) * 64 + ef * 16 + l15] = o[ef][j];
  __syncthreads();
  {
    int e = t & 63, r8 = t >> 6;                // r8 = 0..7
#pragma unroll
    for (int p = 0; p < 2; ++p) {
      int r = r8 * 2 + p;
      float invr = rowInv(r);
      float s8 = 0.f;
#pragma unroll
      for (int wi = 0; wi < 8; ++wi) s8 += redO[wi * 1024 + r * 64 + e];
      Ob[(size_t)(b * S_LEN + q0 + r) * DIM + hh * NHID + e] = f2b(s8 * invr);
    }
  }
}

// ---------------- output projection (R19 verbatim) ----------------
__global__ __launch_bounds__(256) void k_oproj(const u16* __restrict__ Ob,
                                               const u16* __restrict__ Wotb,
                                               const float* __restrict__ bo,
                                               float* __restrict__ out) {
  __shared__ __align__(16) char lds[32768];
  int t = threadIdx.x, w = t >> 6, lane = t & 63;
  int l15 = lane & 15, l4 = lane >> 4;
  int m0 = blockIdx.x * 128, n0 = blockIdx.y * 128;
  int wr = w >> 1, wc = w & 1;
  f32x4 acc[4][4];
  const f32x4 fz = {0.f, 0.f, 0.f, 0.f};
#pragma unroll
  for (int i = 0; i < 4; ++i)
#pragma unroll
    for (int j = 0; j < 4; ++j) acc[i][j] = fz;

  for (int kk = 0; kk < 16; ++kk) {
    int k0 = kk * 64;
#pragma unroll
    for (int c = 0; c < 4; ++c) {
      int idx = c * 256 + t, r = idx >> 3, cb = idx & 7;
      int4 v = *(const int4*)(Ob + (size_t)(m0 + r) * DIM + k0 + cb * 8);
      *(int4*)(lds + r * 128 + ((cb * 16) ^ ((r & 7) << 4))) = v;
    }
#pragma unroll
    for (int c = 0; c < 4; ++c) {
      int idx = c * 256 + t, r = idx >> 3, cb = idx & 7;
      int4 v = *(const int4*)(Wotb + (size_t)(n0 + r) * DIM + k0 + cb * 8);
      *(int4*)(lds + 16384 + r * 128 + ((cb * 16) ^ ((r & 7) << 4))) = v;
    }
    __syncthreads();
    bf16x8 a[4][2], bb[4][2];
#pragma unroll
    for (int mf = 0; mf < 4; ++mf)
#pragma unroll
      for (int kc = 0; kc < 2; ++kc) {
        int row = wr * 64 + mf * 16 + l15;
        int kb = kc * 64 + l4 * 16;
        a[mf][kc] = *(const bf16x8*)(lds + row * 128 + (kb ^ ((row & 7) << 4)));
      }
#pragma unroll
    for (int nf = 0; nf < 4; ++nf)
#pragma unroll
      for (int kc = 0; kc < 2; ++kc) {
        int row = wc * 64 + nf * 16 + l15;
        int kb = kc * 64 + l4 * 16;
        bb[nf][kc] = *(const bf16x8*)(lds + 16384 + row * 128 + (kb ^ ((row & 7) << 4)));
      }
#pragma unroll
    for (int kc = 0; kc < 2; ++kc)
#pragma unroll
      for (int mf = 0; mf < 4; ++mf)
#pragma unroll
        for (int nf = 0; nf < 4; ++nf)
          acc[mf][nf] = mfma16(a[mf][kc], bb[nf][kc], acc[mf][nf]);
    __syncthreads();
  }
#pragma unroll
  for (int nf = 0; nf < 4; ++nf) {
    int n = n0 + wc * 64 + nf * 16 + l15;
    float bv_ = bo[n];
#pragma unroll
    for (int mf = 0; mf < 4; ++mf)
#pragma unroll
      for (int j = 0; j < 4; ++j) {
        int m = m0 + wr * 64 + mf * 16 + l4 * 4 + j;
        out[(size_t)m * DIM + n] = acc[mf][nf][j] + bv_;
      }
  }
}

extern "C" void kernel_launch(void* const* d_in, const int* in_sizes, int n_in,
                              void* d_out, int out_size, void* d_ws, size_t ws_size,
                              hipStream_t stream) {
  const float* x    = (const float*)d_in[0];
  const int*   mask = (const int*)d_in[1];
  const float* Wq   = (const float*)d_in[2];
  const float* bq   = (const float*)d_in[3];
  const float* Wk   = (const float*)d_in[4];
  const float* bk   = (const float*)d_in[5];
  const float* Wv   = (const float*)d_in[6];
  const float* bv   = (const float*)d_in[7];
  const float* Wo   = (const float*)d_in[8];
  const float* bo   = (const float*)d_in[9];
  float* out = (float*)d_out;
  float* alphaOut = out + (size_t)NB * S_LEN * DIM;

  char* ws = (char*)d_ws;
  u16* xb    = (u16*)(ws);             // 8,388,608 B
  u16* Wtb   = (u16*)(ws + 8388608);   // 6,291,456 B
  u16* Wotb  = (u16*)(ws + 14680064);  // 2,097,152 B
  u16* Qb    = (u16*)(ws + 16777216);  // 8,388,608 B
  u16* Kb    = (u16*)(ws + 25165824);  // 8,388,608 B
  u16* Vtb   = (u16*)(ws + 33554432);  // 8,388,608 B
  u16* Ob    = (u16*)(ws + 41943040);  // 8,388,608 B
  uint32_t* mbits = (uint32_t*)(ws + 50331648); // 524,288 B

  k_prep<<<6656, 256, 0, stream>>>(x, mask, Wq, Wk, Wv, Wo, xb, mbits, Wtb, Wotb);
  k_qkv<<<dim3(32, 8, 3), 256, 0, stream>>>(xb, Wtb, bq, bk, bv, Qb, Kb, Vtb);
  k_attn<<<dim3(64, 64), 512, 0, stream>>>(Qb, Kb, Vtb, mbits, alphaOut, Ob);
  k_oproj<<<dim3(32, 8), 256, 0, stream>>>(Ob, Wotb, bo, out);
}

// Round 21
// 212.971 us; speedup vs baseline: 1.0292x; 1.0292x over previous
//
#include <hip/hip_runtime.h>
#include <stdint.h>

#define S_LEN 1024
#define DIM   1024
#define NHID  64
#define NHEAD 16
#define NB    4

typedef __bf16 bf16x8 __attribute__((ext_vector_type(8)));
typedef float  f32x4  __attribute__((ext_vector_type(4)));
typedef unsigned short u16;

__device__ __forceinline__ u16 f2b(float f) {
  unsigned u = __float_as_uint(f);
  u += 0x7FFFu + ((u >> 16) & 1u);          // round-to-nearest-even
  return (u16)(u >> 16);
}

__device__ __forceinline__ f32x4 mfma16(bf16x8 a, bf16x8 b, f32x4 c) {
  return __builtin_amdgcn_mfma_f32_16x16x32_bf16(a, b, c, 0, 0, 0);
}

// ---------------- fused prep: cvt_x + maskbits + 4 transposes, one launch ----------------
__device__ __forceinline__ void transpose_tile(const float* __restrict__ ip,
                                               u16* __restrict__ op,
                                               int R, int C, int r0, int c0,
                                               float (*tile)[65], int t) {
  {
    int col = t & 63, rr = t >> 6;
#pragma unroll
    for (int p = 0; p < 8; ++p) {
      int r = p * 4 + rr;
      tile[r][col] = ip[(size_t)(r0 + r) * C + c0 + col];
    }
  }
  __syncthreads();
  {
    int d = t & 31, er = t >> 5;
#pragma unroll
    for (int p = 0; p < 8; ++p) {
      int e = p * 8 + er;
      op[(size_t)(c0 + e) * R + r0 + d] = f2b(tile[d][e]);
    }
  }
}

__global__ __launch_bounds__(256) void k_prep(const float* __restrict__ x,
                                              const int* __restrict__ mask,
                                              const float* __restrict__ Wq,
                                              const float* __restrict__ Wk,
                                              const float* __restrict__ Wv,
                                              const float* __restrict__ Wo,
                                              u16* __restrict__ xb,
                                              uint32_t* __restrict__ mbits,
                                              u16* __restrict__ Wtb,
                                              u16* __restrict__ Wotb) {
  __shared__ float tile[32][65];
  int blk = blockIdx.x, t = threadIdx.x;
  if (blk < 4096) {
    int i = blk * 256 + t;
    float4 v = ((const float4*)x)[i];
    ushort4 o;
    o.x = f2b(v.x); o.y = f2b(v.y); o.z = f2b(v.z); o.w = f2b(v.w);
    ((ushort4*)xb)[i] = o;
  } else if (blk < 4608) {
    int w = (blk - 4096) * 256 + t;
    const int4* mp = (const int4*)mask + (size_t)w * 8;
    uint32_t v = 0;
#pragma unroll
    for (int i = 0; i < 8; ++i) {
      int4 m = mp[i];
      v |= (m.x != 0 ? 1u : 0u) << (i * 4 + 0);
      v |= (m.y != 0 ? 1u : 0u) << (i * 4 + 1);
      v |= (m.z != 0 ? 1u : 0u) << (i * 4 + 2);
      v |= (m.w != 0 ? 1u : 0u) << (i * 4 + 3);
    }
    mbits[w] = v;
  } else if (blk < 6144) {
    int rel = blk - 4608;                 // 0..1535
    int sel = rel >> 9;                   // /512 -> 0,1,2
    int r2 = rel & 511;
    int batch = r2 >> 5;                  // 0..15
    int r0 = (r2 & 31) * 32;
    const float* W = (sel == 0) ? Wq : (sel == 1) ? Wk : Wv;
    transpose_tile(W + (size_t)batch * 65536,
                   Wtb + (size_t)sel * 1048576 + (size_t)batch * 65536,
                   1024, 64, r0, 0, tile, t);
  } else {
    int rel = blk - 6144;                 // 0..511
    int r0 = (rel >> 4) * 32;
    int c0 = (rel & 15) * 64;
    transpose_tile(Wo, Wotb, 1024, 1024, r0, c0, tile, t);
  }
}

// ---------------- QKV projection: [4096,1024] @ Wt[sel][1024 n][1024 k] ----------------
// Q output is pre-scaled by 0.5 (folds softmax 1/SCALE; exact in bf16)
__global__ __launch_bounds__(256) void k_qkv(const u16* __restrict__ xb,
                                             const u16* __restrict__ Wtb,
                                             const float* __restrict__ bq,
                                             const float* __restrict__ bk,
                                             const float* __restrict__ bv,
                                             u16* __restrict__ Qb,
                                             u16* __restrict__ Kb,
                                             u16* __restrict__ Vtb) {
  __shared__ __align__(16) char lds[32768];
  int t = threadIdx.x, w = t >> 6, lane = t & 63;
  int l15 = lane & 15, l4 = lane >> 4;
  int m0 = blockIdx.x * 128, n0 = blockIdx.y * 128, sel = blockIdx.z;
  const u16* Wh = Wtb + (size_t)sel * (NHEAD * NHID * DIM);
  int wr = w >> 1, wc = w & 1;

  f32x4 acc[4][4];
  const f32x4 fz = {0.f, 0.f, 0.f, 0.f};
#pragma unroll
  for (int i = 0; i < 4; ++i)
#pragma unroll
    for (int j = 0; j < 4; ++j) acc[i][j] = fz;

  for (int kk = 0; kk < 16; ++kk) {
    int k0 = kk * 64;
#pragma unroll
    for (int c = 0; c < 4; ++c) {
      int idx = c * 256 + t, r = idx >> 3, cb = idx & 7;
      int4 v = *(const int4*)(xb + (size_t)(m0 + r) * DIM + k0 + cb * 8);
      *(int4*)(lds + r * 128 + ((cb * 16) ^ ((r & 7) << 4))) = v;
    }
#pragma unroll
    for (int c = 0; c < 4; ++c) {
      int idx = c * 256 + t, r = idx >> 3, cb = idx & 7;
      int4 v = *(const int4*)(Wh + (size_t)(n0 + r) * DIM + k0 + cb * 8);
      *(int4*)(lds + 16384 + r * 128 + ((cb * 16) ^ ((r & 7) << 4))) = v;
    }
    __syncthreads();
    bf16x8 a[4][2], bb[4][2];
#pragma unroll
    for (int mf = 0; mf < 4; ++mf)
#pragma unroll
      for (int kc = 0; kc < 2; ++kc) {
        int row = wr * 64 + mf * 16 + l15;
        int kb = kc * 64 + l4 * 16;
        a[mf][kc] = *(const bf16x8*)(lds + row * 128 + (kb ^ ((row & 7) << 4)));
      }
#pragma unroll
    for (int nf = 0; nf < 4; ++nf)
#pragma unroll
      for (int kc = 0; kc < 2; ++kc) {
        int row = wc * 64 + nf * 16 + l15;
        int kb = kc * 64 + l4 * 16;
        bb[nf][kc] = *(const bf16x8*)(lds + 16384 + row * 128 + (kb ^ ((row & 7) << 4)));
      }
#pragma unroll
    for (int kc = 0; kc < 2; ++kc)
#pragma unroll
      for (int mf = 0; mf < 4; ++mf)
#pragma unroll
        for (int nf = 0; nf < 4; ++nf)
          acc[mf][nf] = mfma16(a[mf][kc], bb[nf][kc], acc[mf][nf]);
    __syncthreads();
  }

  const float* bias = (sel == 0) ? bq : (sel == 1) ? bk : bv;
  float postScale = (sel == 0) ? 0.5f : 1.0f;
#pragma unroll
  for (int nf = 0; nf < 4; ++nf) {
    int n = n0 + wc * 64 + nf * 16 + l15;
    int h = n >> 6, e = n & 63;
    float bv_ = bias[n];
#pragma unroll
    for (int mf = 0; mf < 4; ++mf) {
      int mrow0 = m0 + wr * 64 + mf * 16 + l4 * 4;
      int b_ = mrow0 >> 10, s0 = mrow0 & 1023;
      if (sel == 2) {
        ushort4 pk;
        pk.x = f2b(acc[mf][nf][0] + bv_);
        pk.y = f2b(acc[mf][nf][1] + bv_);
        pk.z = f2b(acc[mf][nf][2] + bv_);
        pk.w = f2b(acc[mf][nf][3] + bv_);
        *(ushort4*)(Vtb + ((size_t)(b_ * NHEAD + h) * NHID + e) * S_LEN + s0) = pk;
      } else {
        u16* dst = (sel == 0) ? Qb : Kb;
#pragma unroll
        for (int j = 0; j < 4; ++j)
          dst[((size_t)(b_ * NHEAD + h) * S_LEN + s0 + j) * NHID + e] =
              f2b((acc[mf][nf][j] + bv_) * postScale);
      }
    }
  }
}

// ---------------- fused attention (banked optimum: LDS-staged P, 4 waves) ----------------
__global__ __launch_bounds__(256) void k_attn(const u16* __restrict__ Qb,
                                              const u16* __restrict__ Kb,
                                              const u16* __restrict__ Vtb,
                                              const uint32_t* __restrict__ mbitsG,
                                              float* __restrict__ alphaOut,
                                              u16* __restrict__ Ob) {
  __shared__ __align__(16) char smem[33024];   // P[16][2048B] + redS[64] f32
  float* redS = (float*)(smem + 32768);
  int t = threadIdx.x, w = t >> 6, lane = t & 63;
  int l15 = lane & 15, l4 = lane >> 4;
  int q0 = blockIdx.x * 16;
  int bh = blockIdx.y, b = bh >> 4, hh = bh & 15;
  const u16* Qh = Qb + (size_t)bh * S_LEN * NHID;
  const u16* Kh = Kb + (size_t)bh * S_LEN * NHID;
  const u16* Vh = Vtb + (size_t)bh * NHID * S_LEN;
  int kbase = w * 256;

  const uint32_t* mrow = mbitsG + ((size_t)b * S_LEN + q0 + l15) * 32 + w * 8;
  uint4 mw0 = *(const uint4*)(mrow);
  uint4 mw1 = *(const uint4*)(mrow + 4);

  bf16x8 aq[2];
#pragma unroll
  for (int ec = 0; ec < 2; ++ec)
    aq[ec] = *(const bf16x8*)(Qh + (size_t)(q0 + l15) * NHID + ec * 32 + l4 * 8);

  const f32x4 fz = {0.f, 0.f, 0.f, 0.f};

  // ---- phase 1: QK^T + exp + mask + stage to P; row sums on the fly ----
  float s0 = 0.f, s1 = 0.f, s2 = 0.f, s3 = 0.f;
#pragma unroll
  for (int kf = 0; kf < 16; ++kf) {
    int key = kbase + kf * 16 + l15;
    bf16x8 kb0 = *(const bf16x8*)(Kh + (size_t)key * NHID + l4 * 8);
    bf16x8 kb1 = *(const bf16x8*)(Kh + (size_t)key * NHID + 32 + l4 * 8);
    f32x4 sct = fz;
    sct = mfma16(kb0, aq[0], sct);              // D[key][q]
    sct = mfma16(kb1, aq[1], sct);
    float e0 = __expf(sct[0]);
    float e1 = __expf(sct[1]);
    float e2 = __expf(sct[2]);
    float e3 = __expf(sct[3]);
    s0 += e0; s1 += e1; s2 += e2; s3 += e3;     // UNMASKED sums (per reference)
    uint32_t mword;
    switch (kf >> 1) {
      case 0: mword = mw0.x; break;
      case 1: mword = mw0.y; break;
      case 2: mword = mw0.z; break;
      case 3: mword = mw0.w; break;
      case 4: mword = mw1.x; break;
      case 5: mword = mw1.y; break;
      case 6: mword = mw1.z; break;
      default: mword = mw1.w; break;
    }
    int bbase = ((kf & 1) << 4) + l4 * 4;
    uint32_t am01 = (((mword >> (bbase + 0)) & 1u) ? 0x0000FFFFu : 0u) |
                    (((mword >> (bbase + 1)) & 1u) ? 0xFFFF0000u : 0u);
    uint32_t am23 = (((mword >> (bbase + 2)) & 1u) ? 0x0000FFFFu : 0u) |
                    (((mword >> (bbase + 3)) & 1u) ? 0xFFFF0000u : 0u);
    uint2 pk;
    pk.x = ((uint32_t)f2b(e0) | ((uint32_t)f2b(e1) << 16)) & am01;
    pk.y = ((uint32_t)f2b(e2) | ((uint32_t)f2b(e3) << 16)) & am23;
    *(uint2*)(smem + l15 * 2048 +
              (((kbase + kf * 16 + l4 * 4) * 2) ^ ((l15 & 7) << 4))) = pk;
  }
  float ls = (s0 + s1) + (s2 + s3);
  ls += __shfl_xor(ls, 16);
  ls += __shfl_xor(ls, 32);                     // slice sum for q-row l15
  if (lane < 16) redS[w * 16 + l15] = ls;
  __syncthreads();                              // P + redS visible to all waves

  float* abW = alphaOut + (size_t)bh * S_LEN * S_LEN;
  f32x4 o[4];
#pragma unroll
  for (int ef = 0; ef < 4; ++ef) o[ef] = fz;

  // phase 2a: write 4 full alpha rows per wave, 1KB contiguous per instruction.
  auto rw = [&](int rr) {
    int r = w * 4 + rr;
    float invr = 1.f / (redS[r] + redS[16 + r] + redS[32 + r] + redS[48 + r]);
    float* dst = abW + (size_t)(q0 + r) * S_LEN;
#pragma unroll
    for (int seg = 0; seg < 4; ++seg) {
      int raw = seg * 512 + lane * 8;           // linear byte offset in P row
      int boff = raw ^ ((r & 7) << 4);          // swizzled LDS address
      uint2 pk = *(const uint2*)(smem + r * 2048 + boff);
      f32x4 av;
      av[0] = __uint_as_float(pk.x << 16) * invr;
      av[1] = __uint_as_float(pk.x & 0xFFFF0000u) * invr;
      av[2] = __uint_as_float(pk.y << 16) * invr;
      av[3] = __uint_as_float(pk.y & 0xFFFF0000u) * invr;
      __builtin_nontemporal_store(av, (f32x4*)(dst + (raw >> 1)));
    }
  };
  // phase 2b: PV over own 256-key slice from LDS P
  auto pvc = [&](int c) {
#pragma unroll
    for (int kc2 = 0; kc2 < 2; ++kc2) {
      bf16x8 pa = *(const bf16x8*)(smem + l15 * 2048 +
          ((((kbase + c * 64 + kc2 * 32) * 2) + l4 * 16) ^ ((l15 & 7) << 4)));
#pragma unroll
      for (int ef = 0; ef < 4; ++ef) {
        int e = ef * 16 + l15;
        bf16x8 vb = *(const bf16x8*)(Vh + (size_t)e * S_LEN + kbase + c * 64 +
                                     kc2 * 32 + l4 * 8);
        o[ef] = mfma16(pa, vb, o[ef]);
      }
    }
  };

  rw(0); pvc(0);
  rw(1); pvc(1);
  rw(2); pvc(2);
  rw(3); pvc(3);

  // epilogue: cross-wave O reduction (redO aliases P rows 0..7), scale by inv
  __syncthreads();
  float* redO = (float*)smem;                   // [4 w][16 q][64 e] = 16KB
#pragma unroll
  for (int ef = 0; ef < 4; ++ef)
#pragma unroll
    for (int j = 0; j < 4; ++j)
      redO[w * 1024 + (l4 * 4 + j) * 64 + ef * 16 + l15] = o[ef][j];
  __syncthreads();
  {
    int e = t & 63, r4 = t >> 6;
#pragma unroll
    for (int p = 0; p < 4; ++p) {
      int r = p * 4 + r4;
      float invr = 1.f / (redS[r] + redS[16 + r] + redS[32 + r] + redS[48 + r]);
      float s4 = redO[r * 64 + e] + redO[1024 + r * 64 + e] +
                 redO[2048 + r * 64 + e] + redO[3072 + r * 64 + e];
      Ob[(size_t)(b * S_LEN + q0 + r) * DIM + hh * NHID + e] = f2b(s4 * invr);
    }
  }
}

// ---------------- output projection ----------------
__global__ __launch_bounds__(256) void k_oproj(const u16* __restrict__ Ob,
                                               const u16* __restrict__ Wotb,
                                               const float* __restrict__ bo,
                                               float* __restrict__ out) {
  __shared__ __align__(16) char lds[32768];
  int t = threadIdx.x, w = t >> 6, lane = t & 63;
  int l15 = lane & 15, l4 = lane >> 4;
  int m0 = blockIdx.x * 128, n0 = blockIdx.y * 128;
  int wr = w >> 1, wc = w & 1;
  f32x4 acc[4][4];
  const f32x4 fz = {0.f, 0.f, 0.f, 0.f};
#pragma unroll
  for (int i = 0; i < 4; ++i)
#pragma unroll
    for (int j = 0; j < 4; ++j) acc[i][j] = fz;

  for (int kk = 0; kk < 16; ++kk) {
    int k0 = kk * 64;
#pragma unroll
    for (int c = 0; c < 4; ++c) {
      int idx = c * 256 + t, r = idx >> 3, cb = idx & 7;
      int4 v = *(const int4*)(Ob + (size_t)(m0 + r) * DIM + k0 + cb * 8);
      *(int4*)(lds + r * 128 + ((cb * 16) ^ ((r & 7) << 4))) = v;
    }
#pragma unroll
    for (int c = 0; c < 4; ++c) {
      int idx = c * 256 + t, r = idx >> 3, cb = idx & 7;
      int4 v = *(const int4*)(Wotb + (size_t)(n0 + r) * DIM + k0 + cb * 8);
      *(int4*)(lds + 16384 + r * 128 + ((cb * 16) ^ ((r & 7) << 4))) = v;
    }
    __syncthreads();
    bf16x8 a[4][2], bb[4][2];
#pragma unroll
    for (int mf = 0; mf < 4; ++mf)
#pragma unroll
      for (int kc = 0; kc < 2; ++kc) {
        int row = wr * 64 + mf * 16 + l15;
        int kb = kc * 64 + l4 * 16;
        a[mf][kc] = *(const bf16x8*)(lds + row * 128 + (kb ^ ((row & 7) << 4)));
      }
#pragma unroll
    for (int nf = 0; nf < 4; ++nf)
#pragma unroll
      for (int kc = 0; kc < 2; ++kc) {
        int row = wc * 64 + nf * 16 + l15;
        int kb = kc * 64 + l4 * 16;
        bb[nf][kc] = *(const bf16x8*)(lds + 16384 + row * 128 + (kb ^ ((row & 7) << 4)));
      }
#pragma unroll
    for (int kc = 0; kc < 2; ++kc)
#pragma unroll
      for (int mf = 0; mf < 4; ++mf)
#pragma unroll
        for (int nf = 0; nf < 4; ++nf)
          acc[mf][nf] = mfma16(a[mf][kc], bb[nf][kc], acc[mf][nf]);
    __syncthreads();
  }
#pragma unroll
  for (int nf = 0; nf < 4; ++nf) {
    int n = n0 + wc * 64 + nf * 16 + l15;
    float bv_ = bo[n];
#pragma unroll
    for (int mf = 0; mf < 4; ++mf)
#pragma unroll
      for (int j = 0; j < 4; ++j) {
        int m = m0 + wr * 64 + mf * 16 + l4 * 4 + j;
        out[(size_t)m * DIM + n] = acc[mf][nf][j] + bv_;
      }
  }
}

extern "C" void kernel_launch(void* const* d_in, const int* in_sizes, int n_in,
                              void* d_out, int out_size, void* d_ws, size_t ws_size,
                              hipStream_t stream) {
  const float* x    = (const float*)d_in[0];
  const int*   mask = (const int*)d_in[1];
  const float* Wq   = (const float*)d_in[2];
  const float* bq   = (const float*)d_in[3];
  const float* Wk   = (const float*)d_in[4];
  const float* bk   = (const float*)d_in[5];
  const float* Wv   = (const float*)d_in[6];
  const float* bv   = (const float*)d_in[7];
  const float* Wo   = (const float*)d_in[8];
  const float* bo   = (const float*)d_in[9];
  float* out = (float*)d_out;
  float* alphaOut = out + (size_t)NB * S_LEN * DIM;

  char* ws = (char*)d_ws;
  u16* xb    = (u16*)(ws);             // 8,388,608 B
  u16* Wtb   = (u16*)(ws + 8388608);   // 6,291,456 B
  u16* Wotb  = (u16*)(ws + 14680064);  // 2,097,152 B
  u16* Qb    = (u16*)(ws + 16777216);  // 8,388,608 B
  u16* Kb    = (u16*)(ws + 25165824);  // 8,388,608 B
  u16* Vtb   = (u16*)(ws + 33554432);  // 8,388,608 B
  u16* Ob    = (u16*)(ws + 41943040);  // 8,388,608 B
  uint32_t* mbits = (uint32_t*)(ws + 50331648); // 524,288 B

  k_prep<<<6656, 256, 0, stream>>>(x, mask, Wq, Wk, Wv, Wo, xb, mbits, Wtb, Wotb);
  k_qkv<<<dim3(32, 8, 3), 256, 0, stream>>>(xb, Wtb, bq, bk, bv, Qb, Kb, Vtb);
  k_attn<<<dim3(64, 64), 256, 0, stream>>>(Qb, Kb, Vtb, mbits, alphaOut, Ob);
  k_oproj<<<dim3(32, 8), 256, 0, stream>>>(Ob, Wotb, bo, out);
}